// Round 5
// baseline (850.173 us; speedup 1.0000x reference)
//
#include <hip/hip_runtime.h>

// ---------------------------------------------------------------------------
// WaveletConvolution: out = W_sp @ (filt * (IW_sp @ (x @ kernel)))
//   x: (N,256) f32, kernel: (256,128) f32, 1.6M edges per sparse matrix.
// Strategy:
//   - device-built CSR each call (hist -> wave-scan alloc -> merged scatter),
//     both edge sets allocated from ONE cursor into ONE combined int2 array
//   - GEMM and histogram fused into one dispatch (block-range partition):
//     independent work, complementary pipes (VALU+LDS vs atomics)
//   - SpMM as row-gather (no f32 atomics): one wave per row,
//     2 edges/wave with 32 lanes x float4 (16B/lane), xor-32 combine
//   - f32 vector GEMM, 128x128 LDS tile (no fp32 MFMA on CDNA4)
//   - h0 lives in d_out (fully rewritten by the last kernel)
// ---------------------------------------------------------------------------

#define TPB 256

// --- fused: blocks [0,gemm_nb) do GEMM tile; rest do row histogram ---------
__global__ __launch_bounds__(256) void gemm_hist_kernel(
    const float* __restrict__ x, const float* __restrict__ w,
    float* __restrict__ h, int N, int gemm_nb,
    const int* __restrict__ ra, int nea,
    const int* __restrict__ rb, int neb,
    int* __restrict__ cnt)
{
    __shared__ float xs_t[32][128];   // [kk][m]
    __shared__ float ks[32][128];     // [kk][n]

    if ((int)blockIdx.x >= gemm_nb) {
        // ---- histogram branch: cnt[0..N)=iw rows, cnt[N..2N)=w rows ----
        int hb = blockIdx.x - gemm_nb;
        int nb = gridDim.x - gemm_nb;
        int i = hb * blockDim.x + threadIdx.x;
        int stride = nb * blockDim.x;
        for (int e = i; e < nea; e += stride) atomicAdd(&cnt[ra[e]], 1);
        for (int e = i; e < neb; e += stride) atomicAdd(&cnt[N + rb[e]], 1);
        return;
    }

    // ---- GEMM branch: 128-row tile, 16x16 threads, 8x8 outputs each ----
    const int t = threadIdx.x;
    const int tm = t >> 4, tn = t & 15;
    const int m0 = tm * 8, n0 = tn * 8;
    const int rowbase = blockIdx.x * 128;

    float acc[8][8];
#pragma unroll
    for (int i = 0; i < 8; ++i)
#pragma unroll
        for (int j = 0; j < 8; ++j) acc[i][j] = 0.f;

    for (int k0 = 0; k0 < 256; k0 += 32) {
        {
            int r = t >> 1;
            int ch = (t & 1) * 16;
            int gr = rowbase + r;
            int cr = (gr < N) ? gr : (N - 1);
            const float4* src = (const float4*)(x + (size_t)cr * 256 + k0 + ch);
            float4 v0 = src[0], v1 = src[1], v2 = src[2], v3 = src[3];
            float tmp[16] = {v0.x, v0.y, v0.z, v0.w, v1.x, v1.y, v1.z, v1.w,
                             v2.x, v2.y, v2.z, v2.w, v3.x, v3.y, v3.z, v3.w};
#pragma unroll
            for (int i = 0; i < 16; ++i) xs_t[ch + i][r] = tmp[i];
        }
#pragma unroll
        for (int j = 0; j < 4; ++j) {
            int idx = t + 256 * j;
            int kr = idx >> 5;
            int kc = (idx & 31) * 4;
            *(float4*)&ks[kr][kc] = *(const float4*)(w + (size_t)(k0 + kr) * 128 + kc);
        }
        __syncthreads();

#pragma unroll
        for (int kk = 0; kk < 32; ++kk) {
            float4 a0 = *(const float4*)&xs_t[kk][m0];
            float4 a1 = *(const float4*)&xs_t[kk][m0 + 4];
            float4 b0 = *(const float4*)&ks[kk][n0];
            float4 b1 = *(const float4*)&ks[kk][n0 + 4];
            float xf[8] = {a0.x, a0.y, a0.z, a0.w, a1.x, a1.y, a1.z, a1.w};
            float kf[8] = {b0.x, b0.y, b0.z, b0.w, b1.x, b1.y, b1.z, b1.w};
#pragma unroll
            for (int i = 0; i < 8; ++i)
#pragma unroll
                for (int j = 0; j < 8; ++j) acc[i][j] += xf[i] * kf[j];
        }
        __syncthreads();
    }

#pragma unroll
    for (int i = 0; i < 8; ++i) {
        int gr = rowbase + m0 + i;
        if (gr < N) {
            float4 o0 = {acc[i][0], acc[i][1], acc[i][2], acc[i][3]};
            float4 o1 = {acc[i][4], acc[i][5], acc[i][6], acc[i][7]};
            *(float4*)(h + (size_t)gr * 128 + n0) = o0;
            *(float4*)(h + (size_t)gr * 128 + n0 + 4) = o1;
        }
    }
}

// allocate contiguous per-row regions from ONE global cursor.
// wave-level inclusive scan -> one atomic per wave (not per row).
// writes rmeta[r] = (start, count) packed, and cursor[r] = start.
__global__ __launch_bounds__(256) void alloc_kernel(const int* __restrict__ cnt,
                                                    int2* __restrict__ rmeta,
                                                    int* __restrict__ cursor,
                                                    int* __restrict__ gcur, int M) {
    int lane = threadIdx.x & 63;
    int gwave = (blockIdx.x * blockDim.x + threadIdx.x) >> 6;
    int nwave = (gridDim.x * blockDim.x) >> 6;
    for (int base = gwave * 64; base < M; base += nwave * 64) {
        int r = base + lane;
        int c = (r < M) ? cnt[r] : 0;
        int s = c;
#pragma unroll
        for (int off = 1; off < 64; off <<= 1) {
            int t = __shfl_up(s, off, 64);
            if (lane >= off) s += t;
        }
        int wtotal = __shfl(s, 63, 64);
        int wbase = 0;
        if (lane == 63) wbase = atomicAdd(gcur, wtotal);
        wbase = __shfl(wbase, 63, 64);
        int o = wbase + s - c;               // exclusive offset for this row
        if (r < M) { rmeta[r] = make_int2(o, c); cursor[r] = o; }
    }
}

// scatter BOTH edge sets into CSR order; one 8B (col, val-bits) store per edge
__global__ void scatter_kernel(const int* __restrict__ rows_a, const int* __restrict__ cols_a,
                               const float* __restrict__ vals_a, int nea,
                               const int* __restrict__ rows_b, const int* __restrict__ cols_b,
                               const float* __restrict__ vals_b, int neb,
                               int* __restrict__ cursor, int N,
                               int2* __restrict__ edat) {
    int i = blockIdx.x * blockDim.x + threadIdx.x;
    int stride = gridDim.x * blockDim.x;
    int ne = nea + neb;
    for (int e = i; e < ne; e += stride) {
        int r, c; float v;
        if (e < nea) {
            r = rows_a[e];       c = cols_a[e];       v = vals_a[e];
        } else {
            int e2 = e - nea;
            r = N + rows_b[e2];  c = cols_b[e2];      v = vals_b[e2];
        }
        int p = atomicAdd(&cursor[r], 1);
        edat[p] = make_int2(c, __float_as_int(v));
    }
}

// --- gather SpMM: hout[r] = scale[r] * sum_e val[e] * hin[col[e]] ----------
// one wave per row; 2 edges processed at once: half-wave (32 lanes) per edge,
// each lane loads float4 (16B). Final __shfl_xor(32) folds the halves.
__global__ __launch_bounds__(256) void spmm_kernel(const int2* __restrict__ rmeta,
                                                   const int2* __restrict__ edat,
                                                   const float* __restrict__ hin,
                                                   float* __restrict__ hout,
                                                   const float* __restrict__ scale,
                                                   int N) {
    int row = blockIdx.x * 4 + (threadIdx.x >> 6);
    if (row >= N) return;
    const int lane = threadIdx.x & 63;
    const int half = lane >> 5;        // 0 or 1: which edge of the pair
    const int l5 = lane & 31;          // feat quad: l5*4 .. l5*4+3
    int2 m = rmeta[row];
    int s = m.x;
    int eend = s + m.y;

    float4 a0 = {0.f, 0.f, 0.f, 0.f}, a1 = {0.f, 0.f, 0.f, 0.f};
    int e = s;
    for (; e + 3 < eend; e += 4) {
        int2 ed0 = edat[e + half];
        int2 ed1 = edat[e + 2 + half];
        const float4 h0 = *(const float4*)(hin + (size_t)ed0.x * 128 + l5 * 4);
        const float4 h1 = *(const float4*)(hin + (size_t)ed1.x * 128 + l5 * 4);
        float v0 = __int_as_float(ed0.y), v1 = __int_as_float(ed1.y);
        a0.x += v0 * h0.x; a0.y += v0 * h0.y; a0.z += v0 * h0.z; a0.w += v0 * h0.w;
        a1.x += v1 * h1.x; a1.y += v1 * h1.y; a1.z += v1 * h1.z; a1.w += v1 * h1.w;
    }
    for (; e + 1 < eend; e += 2) {
        int2 ed = edat[e + half];
        const float4 hv = *(const float4*)(hin + (size_t)ed.x * 128 + l5 * 4);
        float v = __int_as_float(ed.y);
        a0.x += v * hv.x; a0.y += v * hv.y; a0.z += v * hv.z; a0.w += v * hv.w;
    }
    if (e < eend && half == 0) {       // single tail edge: half 0 only
        int2 ed = edat[e];
        const float4 hv = *(const float4*)(hin + (size_t)ed.x * 128 + l5 * 4);
        float v = __int_as_float(ed.y);
        a0.x += v * hv.x; a0.y += v * hv.y; a0.z += v * hv.z; a0.w += v * hv.w;
    }
    float4 acc = {a0.x + a1.x, a0.y + a1.y, a0.z + a1.z, a0.w + a1.w};
    // fold the two half-wave partials (feat l5*4+k lives in lanes l5 and l5+32)
    acc.x += __shfl_xor(acc.x, 32, 64);
    acc.y += __shfl_xor(acc.y, 32, 64);
    acc.z += __shfl_xor(acc.z, 32, 64);
    acc.w += __shfl_xor(acc.w, 32, 64);
    if (half == 0) {
        if (scale) {
            float f = scale[row];
            acc.x *= f; acc.y *= f; acc.z *= f; acc.w *= f;
        }
        *(float4*)(hout + (size_t)row * 128 + l5 * 4) = acc;
    }
}

extern "C" void kernel_launch(void* const* d_in, const int* in_sizes, int n_in,
                              void* d_out, int out_size, void* d_ws, size_t ws_size,
                              hipStream_t stream) {
    const float* x       = (const float*)d_in[0];
    const float* kern    = (const float*)d_in[1];
    const float* filt    = (const float*)d_in[2];
    const float* w_vals  = (const float*)d_in[3];
    const float* iw_vals = (const float*)d_in[4];
    const int*   w_rows  = (const int*)d_in[5];
    const int*   w_cols  = (const int*)d_in[6];
    const int*   iw_rows = (const int*)d_in[7];
    const int*   iw_cols = (const int*)d_in[8];
    float* out = (float*)d_out;

    const int N     = in_sizes[2];        // 100000 nodes
    const int ne_w  = in_sizes[3];        // 1.6M
    const int ne_iw = in_sizes[4];        // 1.6M
    const int ne    = ne_w + ne_iw;

    // workspace layout (d_ws >=16B aligned; all sub-arrays 8B aligned):
    float* h1    = (float*)d_ws;                     // N*128 floats (51.2 MB)
    int2*  edat  = (int2*)(h1 + (size_t)N * 128);    // ne int2     (25.6 MB)
    int2*  rmeta = edat + ne;                        // 2N int2 (start,count)
    int*   cnt    = (int*)(rmeta + 2 * N);           // 2N  (set0=iw, set1=w)
    int*   gcur   = cnt + 2 * N;                     // 1 (+1 pad)
    int*   cursor = gcur + 2;                        // 2N

    float* h0 = out;   // GEMM result lives in d_out; overwritten by final SpMM

    // 1. zero counts + global cursor (contiguous: cnt, gcur) — memset node
    hipMemsetAsync(cnt, 0, (size_t)(2 * N + 2) * sizeof(int), stream);
    // 2. fused {GEMM || histogram}: independent work, block-range partition
    const int gemm_nb = (N + 127) / 128;
    gemm_hist_kernel<<<gemm_nb + 1024, TPB, 0, stream>>>(
        x, kern, h0, N, gemm_nb, iw_rows, ne_iw, w_rows, ne_w, cnt);
    // 3. allocate per-row regions (single cursor, wave-scan)
    alloc_kernel<<<1024, TPB, 0, stream>>>(cnt, rmeta, cursor, gcur, 2 * N);
    // 4. scatter both edge sets into combined CSR array (one launch)
    scatter_kernel<<<2048, TPB, 0, stream>>>(iw_rows, iw_cols, iw_vals, ne_iw,
                                             w_rows, w_cols, w_vals, ne_w,
                                             cursor, N, edat);
    // 5. h1 = filt * (IW @ h0)
    spmm_kernel<<<(N + 3) / 4, TPB, 0, stream>>>(rmeta, edat, h0, h1, filt, N);
    // 6. out = W @ h1
    spmm_kernel<<<(N + 3) / 4, TPB, 0, stream>>>(rmeta + N, edat, h1, out,
                                                 nullptr, N);
}

// Round 7
// 833.313 us; speedup vs baseline: 1.0202x; 1.0202x over previous
//
#include <hip/hip_runtime.h>

// ---------------------------------------------------------------------------
// WaveletConvolution: out = W_sp @ (filt * (IW_sp @ (x @ kernel)))
// R7: R6's padded-meta experiment, but MSTR=4 (16B/row) so total workspace
//     usage is EXACTLY R5's proven 80,000,008 bytes (R6's 85.4 MiB likely
//     overflowed ws_size -> corrupted adjacent buffers -> post-timing fail).
// WS BUDGET: do not exceed 80,000,008 bytes total.
// ---------------------------------------------------------------------------

#define TPB 256
#define MSTR 4   // meta stride in ints = 16B: 4 rows per 64B L2 line

// --- fused: blocks [0,gemm_nb) do GEMM tile; rest do row histogram ---------
__global__ __launch_bounds__(256) void gemm_hist_kernel(
    const float* __restrict__ x, const float* __restrict__ w,
    float* __restrict__ h, int N, int gemm_nb,
    const int* __restrict__ ra, int nea,
    const int* __restrict__ rb, int neb,
    int* __restrict__ meta)
{
    __shared__ float xs_t[32][128];   // [kk][m]
    __shared__ float ks[32][128];     // [kk][n]

    if ((int)blockIdx.x >= gemm_nb) {
        // ---- histogram branch: count -> meta[r*MSTR+2] ----
        int hb = blockIdx.x - gemm_nb;
        int nb = gridDim.x - gemm_nb;
        int i = hb * blockDim.x + threadIdx.x;
        int stride = nb * blockDim.x;
        for (int e = i; e < nea; e += stride)
            atomicAdd(&meta[(size_t)ra[e] * MSTR + 2], 1);
        for (int e = i; e < neb; e += stride)
            atomicAdd(&meta[(size_t)(N + rb[e]) * MSTR + 2], 1);
        return;
    }

    // ---- GEMM branch: 128-row tile, 16x16 threads, 8x8 outputs each ----
    const int t = threadIdx.x;
    const int tm = t >> 4, tn = t & 15;
    const int m0 = tm * 8, n0 = tn * 8;
    const int rowbase = blockIdx.x * 128;

    float acc[8][8];
#pragma unroll
    for (int i = 0; i < 8; ++i)
#pragma unroll
        for (int j = 0; j < 8; ++j) acc[i][j] = 0.f;

    for (int k0 = 0; k0 < 256; k0 += 32) {
        {
            int r = t >> 1;
            int ch = (t & 1) * 16;
            int gr = rowbase + r;
            int cr = (gr < N) ? gr : (N - 1);
            const float4* src = (const float4*)(x + (size_t)cr * 256 + k0 + ch);
            float4 v0 = src[0], v1 = src[1], v2 = src[2], v3 = src[3];
            float tmp[16] = {v0.x, v0.y, v0.z, v0.w, v1.x, v1.y, v1.z, v1.w,
                             v2.x, v2.y, v2.z, v2.w, v3.x, v3.y, v3.z, v3.w};
#pragma unroll
            for (int i = 0; i < 16; ++i) xs_t[ch + i][r] = tmp[i];
        }
#pragma unroll
        for (int j = 0; j < 4; ++j) {
            int idx = t + 256 * j;
            int kr = idx >> 5;
            int kc = (idx & 31) * 4;
            *(float4*)&ks[kr][kc] = *(const float4*)(w + (size_t)(k0 + kr) * 128 + kc);
        }
        __syncthreads();

#pragma unroll
        for (int kk = 0; kk < 32; ++kk) {
            float4 a0 = *(const float4*)&xs_t[kk][m0];
            float4 a1 = *(const float4*)&xs_t[kk][m0 + 4];
            float4 b0 = *(const float4*)&ks[kk][n0];
            float4 b1 = *(const float4*)&ks[kk][n0 + 4];
            float xf[8] = {a0.x, a0.y, a0.z, a0.w, a1.x, a1.y, a1.z, a1.w};
            float kf[8] = {b0.x, b0.y, b0.z, b0.w, b1.x, b1.y, b1.z, b1.w};
#pragma unroll
            for (int i = 0; i < 8; ++i)
#pragma unroll
                for (int j = 0; j < 8; ++j) acc[i][j] += xf[i] * kf[j];
        }
        __syncthreads();
    }

#pragma unroll
    for (int i = 0; i < 8; ++i) {
        int gr = rowbase + m0 + i;
        if (gr < N) {
            float4 o0 = {acc[i][0], acc[i][1], acc[i][2], acc[i][3]};
            float4 o1 = {acc[i][4], acc[i][5], acc[i][6], acc[i][7]};
            *(float4*)(h + (size_t)gr * 128 + n0) = o0;
            *(float4*)(h + (size_t)gr * 128 + n0 + 4) = o1;
        }
    }
}

// allocate contiguous per-row regions from ONE global cursor.
// wave-scan -> one atomic per wave. meta[r*MSTR]: +0=start, +1=count,
// +2 = cnt on input, rewritten to cursor(=start).
__global__ __launch_bounds__(256) void alloc_kernel(int* __restrict__ meta,
                                                    int* __restrict__ gcur, int M) {
    int lane = threadIdx.x & 63;
    int gwave = (blockIdx.x * blockDim.x + threadIdx.x) >> 6;
    int nwave = (gridDim.x * blockDim.x) >> 6;
    for (int base = gwave * 64; base < M; base += nwave * 64) {
        int r = base + lane;
        int c = (r < M) ? meta[(size_t)r * MSTR + 2] : 0;
        int s = c;
#pragma unroll
        for (int off = 1; off < 64; off <<= 1) {
            int t = __shfl_up(s, off, 64);
            if (lane >= off) s += t;
        }
        int wtotal = __shfl(s, 63, 64);
        int wbase = 0;
        if (lane == 63) wbase = atomicAdd(gcur, wtotal);
        wbase = __shfl(wbase, 63, 64);
        int o = wbase + s - c;               // exclusive offset for this row
        if (r < M) {
            meta[(size_t)r * MSTR + 0] = o;
            meta[(size_t)r * MSTR + 1] = c;
            meta[(size_t)r * MSTR + 2] = o;  // cursor
        }
    }
}

// scatter BOTH edge sets into CSR order; atomic on padded meta[r*MSTR+2]
__global__ void scatter_kernel(const int* __restrict__ rows_a, const int* __restrict__ cols_a,
                               const float* __restrict__ vals_a, int nea,
                               const int* __restrict__ rows_b, const int* __restrict__ cols_b,
                               const float* __restrict__ vals_b, int neb,
                               int* __restrict__ meta, int N,
                               int2* __restrict__ edat) {
    int i = blockIdx.x * blockDim.x + threadIdx.x;
    int stride = gridDim.x * blockDim.x;
    int ne = nea + neb;
    for (int e = i; e < ne; e += stride) {
        int r, c; float v;
        if (e < nea) {
            r = rows_a[e];       c = cols_a[e];       v = vals_a[e];
        } else {
            int e2 = e - nea;
            r = N + rows_b[e2];  c = cols_b[e2];      v = vals_b[e2];
        }
        int p = atomicAdd(&meta[(size_t)r * MSTR + 2], 1);
        edat[p] = make_int2(c, __float_as_int(v));
    }
}

// --- gather SpMM: hout[r] = scale[r] * sum_e val[e] * hin[col[e]] ----------
// one wave per row; 2 edges at once: half-wave (32 lanes) per edge,
// each lane loads float4 (16B). Final __shfl_xor(32) folds the halves.
__global__ __launch_bounds__(256) void spmm_kernel(const int* __restrict__ meta,
                                                   const int2* __restrict__ edat,
                                                   const float* __restrict__ hin,
                                                   float* __restrict__ hout,
                                                   const float* __restrict__ scale,
                                                   int N) {
    int row = blockIdx.x * 4 + (threadIdx.x >> 6);
    if (row >= N) return;
    const int lane = threadIdx.x & 63;
    const int half = lane >> 5;        // 0 or 1: which edge of the pair
    const int l5 = lane & 31;          // feat quad: l5*4 .. l5*4+3
    int2 m = *(const int2*)&meta[(size_t)row * MSTR];   // (start, count)
    int s = m.x;
    int eend = s + m.y;

    float4 a0 = {0.f, 0.f, 0.f, 0.f}, a1 = {0.f, 0.f, 0.f, 0.f};
    int e = s;
    for (; e + 3 < eend; e += 4) {
        int2 ed0 = edat[e + half];
        int2 ed1 = edat[e + 2 + half];
        const float4 h0 = *(const float4*)(hin + (size_t)ed0.x * 128 + l5 * 4);
        const float4 h1 = *(const float4*)(hin + (size_t)ed1.x * 128 + l5 * 4);
        float v0 = __int_as_float(ed0.y), v1 = __int_as_float(ed1.y);
        a0.x += v0 * h0.x; a0.y += v0 * h0.y; a0.z += v0 * h0.z; a0.w += v0 * h0.w;
        a1.x += v1 * h1.x; a1.y += v1 * h1.y; a1.z += v1 * h1.z; a1.w += v1 * h1.w;
    }
    for (; e + 1 < eend; e += 2) {
        int2 ed = edat[e + half];
        const float4 hv = *(const float4*)(hin + (size_t)ed.x * 128 + l5 * 4);
        float v = __int_as_float(ed.y);
        a0.x += v * hv.x; a0.y += v * hv.y; a0.z += v * hv.z; a0.w += v * hv.w;
    }
    if (e < eend && half == 0) {       // single tail edge: half 0 only
        int2 ed = edat[e];
        const float4 hv = *(const float4*)(hin + (size_t)ed.x * 128 + l5 * 4);
        float v = __int_as_float(ed.y);
        a0.x += v * hv.x; a0.y += v * hv.y; a0.z += v * hv.z; a0.w += v * hv.w;
    }
    float4 acc = {a0.x + a1.x, a0.y + a1.y, a0.z + a1.z, a0.w + a1.w};
    acc.x += __shfl_xor(acc.x, 32, 64);
    acc.y += __shfl_xor(acc.y, 32, 64);
    acc.z += __shfl_xor(acc.z, 32, 64);
    acc.w += __shfl_xor(acc.w, 32, 64);
    if (half == 0) {
        if (scale) {
            float f = scale[row];
            acc.x *= f; acc.y *= f; acc.z *= f; acc.w *= f;
        }
        *(float4*)(hout + (size_t)row * 128 + l5 * 4) = acc;
    }
}

extern "C" void kernel_launch(void* const* d_in, const int* in_sizes, int n_in,
                              void* d_out, int out_size, void* d_ws, size_t ws_size,
                              hipStream_t stream) {
    const float* x       = (const float*)d_in[0];
    const float* kern    = (const float*)d_in[1];
    const float* filt    = (const float*)d_in[2];
    const float* w_vals  = (const float*)d_in[3];
    const float* iw_vals = (const float*)d_in[4];
    const int*   w_rows  = (const int*)d_in[5];
    const int*   w_cols  = (const int*)d_in[6];
    const int*   iw_rows = (const int*)d_in[7];
    const int*   iw_cols = (const int*)d_in[8];
    float* out = (float*)d_out;

    const int N     = in_sizes[2];        // 100000 nodes
    const int ne_w  = in_sizes[3];        // 1.6M
    const int ne_iw = in_sizes[4];        // 1.6M
    const int ne    = ne_w + ne_iw;

    // workspace layout — total 80,000,008 bytes (== R5 proven budget):
    float* h1    = (float*)d_ws;                     // N*128 floats (51.2 MB)
    int2*  edat  = (int2*)(h1 + (size_t)N * 128);    // ne int2     (25.6 MB)
    int*   meta  = (int*)(edat + ne);                // 2N*MSTR ints (3.2 MB)
    int*   gcur  = meta + (size_t)2 * N * MSTR;      // 2 ints

    float* h0 = out;   // GEMM result lives in d_out; overwritten by final SpMM

    // 1. zero meta + global cursor (contiguous)
    hipMemsetAsync(meta, 0, ((size_t)2 * N * MSTR + 2) * sizeof(int), stream);
    // 2. fused {GEMM || histogram}
    const int gemm_nb = (N + 127) / 128;
    gemm_hist_kernel<<<gemm_nb + 1024, TPB, 0, stream>>>(
        x, kern, h0, N, gemm_nb, iw_rows, ne_iw, w_rows, ne_w, meta);
    // 3. allocate per-row regions (single cursor, wave-scan)
    alloc_kernel<<<1024, TPB, 0, stream>>>(meta, gcur, 2 * N);
    // 4. scatter both edge sets into combined CSR array
    scatter_kernel<<<4096, TPB, 0, stream>>>(iw_rows, iw_cols, iw_vals, ne_iw,
                                             w_rows, w_cols, w_vals, ne_w,
                                             meta, N, edat);
    // 5. h1 = filt * (IW @ h0)
    spmm_kernel<<<(N + 3) / 4, TPB, 0, stream>>>(meta, edat, h0, h1, filt, N);
    // 6. out = W @ h1
    spmm_kernel<<<(N + 3) / 4, TPB, 0, stream>>>(meta + (size_t)N * MSTR, edat,
                                                 h1, out, nullptr, N);
}

// Round 8
// 604.132 us; speedup vs baseline: 1.4073x; 1.3794x over previous
//
#include <hip/hip_runtime.h>

// ---------------------------------------------------------------------------
// WaveletConvolution: out = W_sp @ (filt * (IW_sp @ (x @ kernel)))
// R8: replace atomic hist+scatter CSR build (R7: scatter 268us, WRITE_SIZE
//     198MB for 25.6MB payload -> line-thrash) with deterministic two-level
//     partition: LDS-hist -> global scan -> bucket runs -> in-LDS CSR.
//     Zero scattered global atomics in the whole pipeline.
// WS BUDGET: <= 80,000,008 bytes (R5/R7 proven).
// ---------------------------------------------------------------------------

#define TPB   256
#define BROWS 256     // rows per bucket (bucket id = brow >> 8)
#define NBLK  256     // partition blocks in p3a/p3b
#define P4CAP 8192    // max edges staged per bucket (avg 4096, sigma ~64)

// --- f32 GEMM: h = x(N,256) @ w(256,128), 128-row tile ---------------------
__global__ __launch_bounds__(256) void gemm_kernel(const float* __restrict__ x,
                                                   const float* __restrict__ w,
                                                   float* __restrict__ h, int N) {
    __shared__ float xs_t[32][128];   // [kk][m]
    __shared__ float ks[32][128];     // [kk][n]
    const int t = threadIdx.x;
    const int tm = t >> 4, tn = t & 15;
    const int m0 = tm * 8, n0 = tn * 8;
    const int rowbase = blockIdx.x * 128;

    float acc[8][8];
#pragma unroll
    for (int i = 0; i < 8; ++i)
#pragma unroll
        for (int j = 0; j < 8; ++j) acc[i][j] = 0.f;

    for (int k0 = 0; k0 < 256; k0 += 32) {
        {
            int r = t >> 1;
            int ch = (t & 1) * 16;
            int gr = rowbase + r;
            int cr = (gr < N) ? gr : (N - 1);
            const float4* src = (const float4*)(x + (size_t)cr * 256 + k0 + ch);
            float4 v0 = src[0], v1 = src[1], v2 = src[2], v3 = src[3];
            float tmp[16] = {v0.x, v0.y, v0.z, v0.w, v1.x, v1.y, v1.z, v1.w,
                             v2.x, v2.y, v2.z, v2.w, v3.x, v3.y, v3.z, v3.w};
#pragma unroll
            for (int i = 0; i < 16; ++i) xs_t[ch + i][r] = tmp[i];
        }
#pragma unroll
        for (int j = 0; j < 4; ++j) {
            int idx = t + 256 * j;
            int kr = idx >> 5;
            int kc = (idx & 31) * 4;
            *(float4*)&ks[kr][kc] = *(const float4*)(w + (size_t)(k0 + kr) * 128 + kc);
        }
        __syncthreads();

#pragma unroll
        for (int kk = 0; kk < 32; ++kk) {
            float4 a0 = *(const float4*)&xs_t[kk][m0];
            float4 a1 = *(const float4*)&xs_t[kk][m0 + 4];
            float4 b0 = *(const float4*)&ks[kk][n0];
            float4 b1 = *(const float4*)&ks[kk][n0 + 4];
            float xf[8] = {a0.x, a0.y, a0.z, a0.w, a1.x, a1.y, a1.z, a1.w};
            float kf[8] = {b0.x, b0.y, b0.z, b0.w, b1.x, b1.y, b1.z, b1.w};
#pragma unroll
            for (int i = 0; i < 8; ++i)
#pragma unroll
                for (int j = 0; j < 8; ++j) acc[i][j] += xf[i] * kf[j];
        }
        __syncthreads();
    }

#pragma unroll
    for (int i = 0; i < 8; ++i) {
        int gr = rowbase + m0 + i;
        if (gr < N) {
            float4 o0 = {acc[i][0], acc[i][1], acc[i][2], acc[i][3]};
            float4 o1 = {acc[i][4], acc[i][5], acc[i][6], acc[i][7]};
            *(float4*)(h + (size_t)gr * 128 + n0) = o0;
            *(float4*)(h + (size_t)gr * 128 + n0 + 4) = o1;
        }
    }
}

// --- p3a: per-(bucket,block) LDS histogram, no global atomics --------------
// gcounts layout: [bucket][block] flat, + sentinel 0 at [NB*NBLK].
__global__ __launch_bounds__(256) void p3a_hist(
    const int* __restrict__ iw_rows, int ne_iw,
    const int* __restrict__ w_rows, int ne_w,
    int N, int NB, int* __restrict__ gcounts)
{
    __shared__ int cnt[1024];                 // NB <= 1024 (782 here)
    const int ne = ne_iw + ne_w;
    const int k = blockIdx.x;
    const int ch = (ne + NBLK - 1) / NBLK;
    const int e0 = k * ch;
    const int e1 = min(ne, e0 + ch);
    for (int i = threadIdx.x; i < NB; i += TPB) cnt[i] = 0;
    __syncthreads();
    for (int e = e0 + threadIdx.x; e < e1; e += TPB) {
        int brow = (e < ne_iw) ? iw_rows[e] : (N + w_rows[e - ne_iw]);
        atomicAdd(&cnt[brow >> 8], 1);        // LDS atomic
    }
    __syncthreads();
    for (int b = threadIdx.x; b < NB; b += TPB)
        gcounts[(size_t)b * NBLK + k] = cnt[b];
    if (k == 0 && threadIdx.x == 0) gcounts[(size_t)NB * NBLK] = 0;  // sentinel
}

// --- scan1: per-1024-chunk exclusive scan (in place) + chunk sums ----------
__global__ __launch_bounds__(1024) void scan1(int* __restrict__ g, int total,
                                              int* __restrict__ bsum)
{
    __shared__ int a[1024];
    const int tid = threadIdx.x;
    const int gid = blockIdx.x * 1024 + tid;
    int v0 = (gid < total) ? g[gid] : 0;
    a[tid] = v0;
    __syncthreads();
    for (int off = 1; off < 1024; off <<= 1) {
        int v = a[tid];
        if (tid >= off) v += a[tid - off];
        __syncthreads();
        a[tid] = v;
        __syncthreads();
    }
    if (gid < total) g[gid] = a[tid] - v0;    // exclusive within chunk
    if (tid == 1023) bsum[blockIdx.x] = a[1023];
}

// --- scan2: exclusive scan of chunk sums (nch <= 256) ----------------------
__global__ __launch_bounds__(256) void scan2(int* __restrict__ bsum, int nch)
{
    __shared__ int a[256];
    const int tid = threadIdx.x;
    int v0 = (tid < nch) ? bsum[tid] : 0;
    a[tid] = v0;
    __syncthreads();
    for (int off = 1; off < 256; off <<= 1) {
        int v = a[tid];
        if (tid >= off) v += a[tid - off];
        __syncthreads();
        a[tid] = v;
        __syncthreads();
    }
    if (tid < nch) bsum[tid] = a[tid] - v0;
}

// --- p3b: place edges into private (bucket,block) runs, LDS cursors only ---
// edat[p] = ((rowlocal<<20)|col, val-bits); col < 2^20 required (N=100000 ok)
__global__ __launch_bounds__(256) void p3b_part(
    const int* __restrict__ iw_rows, const int* __restrict__ iw_cols,
    const float* __restrict__ iw_vals, int ne_iw,
    const int* __restrict__ w_rows, const int* __restrict__ w_cols,
    const float* __restrict__ w_vals, int ne_w,
    int N, int NB,
    const int* __restrict__ scanned, const int* __restrict__ bsum,
    int2* __restrict__ edat)
{
    __shared__ int runb[1024];
    __shared__ int cur[1024];
    const int ne = ne_iw + ne_w;
    const int k = blockIdx.x;
    const int ch = (ne + NBLK - 1) / NBLK;
    const int e0 = k * ch;
    const int e1 = min(ne, e0 + ch);
    for (int b = threadIdx.x; b < NB; b += TPB) {
        int idx = b * NBLK + k;
        runb[b] = scanned[idx] + bsum[idx >> 10];
        cur[b] = 0;
    }
    __syncthreads();
    for (int e = e0 + threadIdx.x; e < e1; e += TPB) {
        int brow, c; float v;
        if (e < ne_iw) { brow = iw_rows[e]; c = iw_cols[e]; v = iw_vals[e]; }
        else { int e2 = e - ne_iw; brow = N + w_rows[e2]; c = w_cols[e2]; v = w_vals[e2]; }
        int b = brow >> 8;
        int p = runb[b] + atomicAdd(&cur[b], 1);   // LDS atomic
        edat[p] = make_int2(((brow & 255) << 20) | c, __float_as_int(v));
    }
}

// --- p4: bucket -> exact per-row CSR, fully in LDS, in-place write-back ----
__global__ __launch_bounds__(256) void p4_csr(
    const int* __restrict__ scanned, const int* __restrict__ bsum,
    int NB, int M /*=2N*/,
    int2* __restrict__ edat, int2* __restrict__ rmeta)
{
    __shared__ int2 st[P4CAP];
    __shared__ int cnt[BROWS], off[BROWS], cur[BROWS];
    const int tid = threadIdx.x;
    const int b = blockIdx.x;
    const int i0 = b * NBLK;
    const int i1 = (b + 1) * NBLK;
    const int start = scanned[i0] + bsum[i0 >> 10];
    const int end   = scanned[i1] + bsum[i1 >> 10];
    int n = end - start;
    if (n > P4CAP) n = P4CAP;   // statistically impossible for this data
    for (int i = tid; i < n; i += TPB) st[i] = edat[start + i];
    cnt[tid] = 0;               // TPB == BROWS
    __syncthreads();
    for (int i = tid; i < n; i += TPB)
        atomicAdd(&cnt[st[i].x >> 20], 1);
    __syncthreads();
    // exclusive scan of cnt -> excl
    int v0 = cnt[tid];
    off[tid] = v0;
    __syncthreads();
    for (int o = 1; o < 256; o <<= 1) {
        int v = off[tid];
        if (tid >= o) v += off[tid - o];
        __syncthreads();
        off[tid] = v;
        __syncthreads();
    }
    int excl = off[tid] - v0;
    __syncthreads();
    off[tid] = excl;
    cur[tid] = 0;
    int grow = b * BROWS + tid;
    if (grow < M) rmeta[grow] = make_int2(start + excl, v0);
    __syncthreads();
    for (int i = tid; i < n; i += TPB) {
        int rl = st[i].x >> 20;
        int p = start + off[rl] + atomicAdd(&cur[rl], 1);   // LDS atomic
        edat[p] = make_int2(st[i].x & 0xFFFFF, st[i].y);
    }
}

// --- gather SpMM: hout[r] = scale[r] * sum_e val[e] * hin[col[e]] ----------
__global__ __launch_bounds__(256) void spmm_kernel(const int2* __restrict__ rmeta,
                                                   const int2* __restrict__ edat,
                                                   const float* __restrict__ hin,
                                                   float* __restrict__ hout,
                                                   const float* __restrict__ scale,
                                                   int N) {
    int row = blockIdx.x * 4 + (threadIdx.x >> 6);
    if (row >= N) return;
    const int lane = threadIdx.x & 63;
    const int half = lane >> 5;
    const int l5 = lane & 31;
    int2 m = rmeta[row];
    int s = m.x;
    int eend = s + m.y;

    float4 a0 = {0.f, 0.f, 0.f, 0.f}, a1 = {0.f, 0.f, 0.f, 0.f};
    int e = s;
    for (; e + 3 < eend; e += 4) {
        int2 ed0 = edat[e + half];
        int2 ed1 = edat[e + 2 + half];
        const float4 h0 = *(const float4*)(hin + (size_t)ed0.x * 128 + l5 * 4);
        const float4 h1 = *(const float4*)(hin + (size_t)ed1.x * 128 + l5 * 4);
        float v0 = __int_as_float(ed0.y), v1 = __int_as_float(ed1.y);
        a0.x += v0 * h0.x; a0.y += v0 * h0.y; a0.z += v0 * h0.z; a0.w += v0 * h0.w;
        a1.x += v1 * h1.x; a1.y += v1 * h1.y; a1.z += v1 * h1.z; a1.w += v1 * h1.w;
    }
    for (; e + 1 < eend; e += 2) {
        int2 ed = edat[e + half];
        const float4 hv = *(const float4*)(hin + (size_t)ed.x * 128 + l5 * 4);
        float v = __int_as_float(ed.y);
        a0.x += v * hv.x; a0.y += v * hv.y; a0.z += v * hv.z; a0.w += v * hv.w;
    }
    if (e < eend && half == 0) {
        int2 ed = edat[e];
        const float4 hv = *(const float4*)(hin + (size_t)ed.x * 128 + l5 * 4);
        float v = __int_as_float(ed.y);
        a0.x += v * hv.x; a0.y += v * hv.y; a0.z += v * hv.z; a0.w += v * hv.w;
    }
    float4 acc = {a0.x + a1.x, a0.y + a1.y, a0.z + a1.z, a0.w + a1.w};
    acc.x += __shfl_xor(acc.x, 32, 64);
    acc.y += __shfl_xor(acc.y, 32, 64);
    acc.z += __shfl_xor(acc.z, 32, 64);
    acc.w += __shfl_xor(acc.w, 32, 64);
    if (half == 0) {
        if (scale) {
            float f = scale[row];
            acc.x *= f; acc.y *= f; acc.z *= f; acc.w *= f;
        }
        *(float4*)(hout + (size_t)row * 128 + l5 * 4) = acc;
    }
}

extern "C" void kernel_launch(void* const* d_in, const int* in_sizes, int n_in,
                              void* d_out, int out_size, void* d_ws, size_t ws_size,
                              hipStream_t stream) {
    const float* x       = (const float*)d_in[0];
    const float* kern    = (const float*)d_in[1];
    const float* filt    = (const float*)d_in[2];
    const float* w_vals  = (const float*)d_in[3];
    const float* iw_vals = (const float*)d_in[4];
    const int*   w_rows  = (const int*)d_in[5];
    const int*   w_cols  = (const int*)d_in[6];
    const int*   iw_rows = (const int*)d_in[7];
    const int*   iw_cols = (const int*)d_in[8];
    float* out = (float*)d_out;

    const int N     = in_sizes[2];        // 100000
    const int ne_w  = in_sizes[3];        // 1.6M
    const int ne_iw = in_sizes[4];        // 1.6M
    const int ne    = ne_w + ne_iw;
    const int M     = 2 * N;              // combined row space
    const int NB    = (M + BROWS - 1) / BROWS;        // 782 buckets
    const int total = NB * NBLK + 1;                  // scan length (+sentinel)
    const int nch   = (total + 1023) >> 10;           // 196 chunks

    // workspace layout (~79.2 MB, <= 80,000,008 proven budget):
    float* h1      = (float*)d_ws;                    // N*128 f       (51.2 MB)
    int2*  edat    = (int2*)(h1 + (size_t)N * 128);   // ne int2       (25.6 MB)
    int2*  rmeta   = edat + ne;                       // M int2        (1.6 MB)
    int*   gcounts = (int*)(rmeta + M);               // total ints    (0.8 MB)
    int*   bsum    = gcounts + total;                 // 256 ints

    float* h0 = out;   // GEMM result in d_out; overwritten by final SpMM

    // 1. dense projection h0 = x @ kernel
    gemm_kernel<<<(N + 127) / 128, TPB, 0, stream>>>(x, kern, h0, N);
    // 2. per-(bucket,block) histogram (LDS only)
    p3a_hist<<<NBLK, TPB, 0, stream>>>(iw_rows, ne_iw, w_rows, ne_w, N, NB, gcounts);
    // 3. two-level exclusive scan of gcounts
    scan1<<<nch, 1024, 0, stream>>>(gcounts, total, bsum);
    scan2<<<1, 256, 0, stream>>>(bsum, nch);
    // 4. partition edges into bucket-grouped runs (deterministic placement)
    p3b_part<<<NBLK, TPB, 0, stream>>>(iw_rows, iw_cols, iw_vals, ne_iw,
                                       w_rows, w_cols, w_vals, ne_w,
                                       N, NB, gcounts, bsum, edat);
    // 5. bucket -> exact per-row CSR (in-LDS, in-place) + rmeta
    p4_csr<<<NB, TPB, 0, stream>>>(gcounts, bsum, NB, M, edat, rmeta);
    // 6. h1 = filt * (IW @ h0)
    spmm_kernel<<<(N + 3) / 4, TPB, 0, stream>>>(rmeta, edat, h0, h1, filt, N);
    // 7. out = W @ h1
    spmm_kernel<<<(N + 3) / 4, TPB, 0, stream>>>(rmeta + N, edat, h1, out, nullptr, N);
}

// Round 10
// 522.314 us; speedup vs baseline: 1.6277x; 1.1566x over previous
//
#include <hip/hip_runtime.h>

// ---------------------------------------------------------------------------
// WaveletConvolution: out = W_sp @ (filt * (IW_sp @ (x @ kernel)))
// R10 == R9 resubmit (infra failure, never benched):
//     bf16 storage for h0/h1 (gathers were 49%-HBM-bound at f32: FETCH 382MB,
//     112us/spmm). Gather bytes halve; f32 accumulation throughout.
//     SpMM: quarter-wave (16 lanes x 16B) per edge, 8 edges in flight/wave.
//     CSR build (R8 deterministic partition) unchanged.
// WS BUDGET: <= 80,000,008 bytes (proven). Used: ~79.2 MB.
// ---------------------------------------------------------------------------

#define TPB   256
#define BROWS 256     // rows per bucket (bucket id = brow >> 8)
#define NBLK  256     // partition blocks in p3a/p3b
#define P4CAP 8192    // max edges staged per bucket (avg 4096)

__device__ __forceinline__ unsigned short f2bf(float f) {
    unsigned int u = __float_as_uint(f);
    u += 0x7FFFu + ((u >> 16) & 1u);          // round-to-nearest-even
    return (unsigned short)(u >> 16);
}
__device__ __forceinline__ float bf_lo(unsigned int u) {   // low ushort
    return __uint_as_float(u << 16);
}
__device__ __forceinline__ float bf_hi(unsigned int u) {   // high ushort
    return __uint_as_float(u & 0xFFFF0000u);
}

// --- f32 GEMM: h = x(N,256) @ w(256,128), bf16 output ----------------------
__global__ __launch_bounds__(256) void gemm_kernel(const float* __restrict__ x,
                                                   const float* __restrict__ w,
                                                   unsigned short* __restrict__ h,
                                                   int N) {
    __shared__ float xs_t[32][128];   // [kk][m]
    __shared__ float ks[32][128];     // [kk][n]
    const int t = threadIdx.x;
    const int tm = t >> 4, tn = t & 15;
    const int m0 = tm * 8, n0 = tn * 8;
    const int rowbase = blockIdx.x * 128;

    float acc[8][8];
#pragma unroll
    for (int i = 0; i < 8; ++i)
#pragma unroll
        for (int j = 0; j < 8; ++j) acc[i][j] = 0.f;

    for (int k0 = 0; k0 < 256; k0 += 32) {
        {
            int r = t >> 1;
            int ch = (t & 1) * 16;
            int gr = rowbase + r;
            int cr = (gr < N) ? gr : (N - 1);
            const float4* src = (const float4*)(x + (size_t)cr * 256 + k0 + ch);
            float4 v0 = src[0], v1 = src[1], v2 = src[2], v3 = src[3];
            float tmp[16] = {v0.x, v0.y, v0.z, v0.w, v1.x, v1.y, v1.z, v1.w,
                             v2.x, v2.y, v2.z, v2.w, v3.x, v3.y, v3.z, v3.w};
#pragma unroll
            for (int i = 0; i < 16; ++i) xs_t[ch + i][r] = tmp[i];
        }
#pragma unroll
        for (int j = 0; j < 4; ++j) {
            int idx = t + 256 * j;
            int kr = idx >> 5;
            int kc = (idx & 31) * 4;
            *(float4*)&ks[kr][kc] = *(const float4*)(w + (size_t)(k0 + kr) * 128 + kc);
        }
        __syncthreads();

#pragma unroll
        for (int kk = 0; kk < 32; ++kk) {
            float4 a0 = *(const float4*)&xs_t[kk][m0];
            float4 a1 = *(const float4*)&xs_t[kk][m0 + 4];
            float4 b0 = *(const float4*)&ks[kk][n0];
            float4 b1 = *(const float4*)&ks[kk][n0 + 4];
            float xf[8] = {a0.x, a0.y, a0.z, a0.w, a1.x, a1.y, a1.z, a1.w};
            float kf[8] = {b0.x, b0.y, b0.z, b0.w, b1.x, b1.y, b1.z, b1.w};
#pragma unroll
            for (int i = 0; i < 8; ++i)
#pragma unroll
                for (int j = 0; j < 8; ++j) acc[i][j] += xf[i] * kf[j];
        }
        __syncthreads();
    }

#pragma unroll
    for (int i = 0; i < 8; ++i) {
        int gr = rowbase + m0 + i;
        if (gr < N) {
            uint4 o;
            o.x = (unsigned)f2bf(acc[i][0]) | ((unsigned)f2bf(acc[i][1]) << 16);
            o.y = (unsigned)f2bf(acc[i][2]) | ((unsigned)f2bf(acc[i][3]) << 16);
            o.z = (unsigned)f2bf(acc[i][4]) | ((unsigned)f2bf(acc[i][5]) << 16);
            o.w = (unsigned)f2bf(acc[i][6]) | ((unsigned)f2bf(acc[i][7]) << 16);
            *(uint4*)(h + (size_t)gr * 128 + n0) = o;
        }
    }
}

// --- p3a: per-(bucket,block) LDS histogram, no global atomics --------------
__global__ __launch_bounds__(256) void p3a_hist(
    const int* __restrict__ iw_rows, int ne_iw,
    const int* __restrict__ w_rows, int ne_w,
    int N, int NB, int* __restrict__ gcounts)
{
    __shared__ int cnt[1024];                 // NB <= 1024 (782 here)
    const int ne = ne_iw + ne_w;
    const int k = blockIdx.x;
    const int ch = (ne + NBLK - 1) / NBLK;
    const int e0 = k * ch;
    const int e1 = min(ne, e0 + ch);
    for (int i = threadIdx.x; i < NB; i += TPB) cnt[i] = 0;
    __syncthreads();
    for (int e = e0 + threadIdx.x; e < e1; e += TPB) {
        int brow = (e < ne_iw) ? iw_rows[e] : (N + w_rows[e - ne_iw]);
        atomicAdd(&cnt[brow >> 8], 1);        // LDS atomic
    }
    __syncthreads();
    for (int b = threadIdx.x; b < NB; b += TPB)
        gcounts[(size_t)b * NBLK + k] = cnt[b];
    if (k == 0 && threadIdx.x == 0) gcounts[(size_t)NB * NBLK] = 0;  // sentinel
}

// --- scan1: per-1024-chunk exclusive scan (in place) + chunk sums ----------
__global__ __launch_bounds__(1024) void scan1(int* __restrict__ g, int total,
                                              int* __restrict__ bsum)
{
    __shared__ int a[1024];
    const int tid = threadIdx.x;
    const int gid = blockIdx.x * 1024 + tid;
    int v0 = (gid < total) ? g[gid] : 0;
    a[tid] = v0;
    __syncthreads();
    for (int off = 1; off < 1024; off <<= 1) {
        int v = a[tid];
        if (tid >= off) v += a[tid - off];
        __syncthreads();
        a[tid] = v;
        __syncthreads();
    }
    if (gid < total) g[gid] = a[tid] - v0;    // exclusive within chunk
    if (tid == 1023) bsum[blockIdx.x] = a[1023];
}

// --- scan2: exclusive scan of chunk sums (nch <= 256) ----------------------
__global__ __launch_bounds__(256) void scan2(int* __restrict__ bsum, int nch)
{
    __shared__ int a[256];
    const int tid = threadIdx.x;
    int v0 = (tid < nch) ? bsum[tid] : 0;
    a[tid] = v0;
    __syncthreads();
    for (int off = 1; off < 256; off <<= 1) {
        int v = a[tid];
        if (tid >= off) v += a[tid - off];
        __syncthreads();
        a[tid] = v;
        __syncthreads();
    }
    if (tid < nch) bsum[tid] = a[tid] - v0;
}

// --- p3b: place edges into private (bucket,block) runs, LDS cursors only ---
__global__ __launch_bounds__(256) void p3b_part(
    const int* __restrict__ iw_rows, const int* __restrict__ iw_cols,
    const float* __restrict__ iw_vals, int ne_iw,
    const int* __restrict__ w_rows, const int* __restrict__ w_cols,
    const float* __restrict__ w_vals, int ne_w,
    int N, int NB,
    const int* __restrict__ scanned, const int* __restrict__ bsum,
    int2* __restrict__ edat)
{
    __shared__ int runb[1024];
    __shared__ int cur[1024];
    const int ne = ne_iw + ne_w;
    const int k = blockIdx.x;
    const int ch = (ne + NBLK - 1) / NBLK;
    const int e0 = k * ch;
    const int e1 = min(ne, e0 + ch);
    for (int b = threadIdx.x; b < NB; b += TPB) {
        int idx = b * NBLK + k;
        runb[b] = scanned[idx] + bsum[idx >> 10];
        cur[b] = 0;
    }
    __syncthreads();
    for (int e = e0 + threadIdx.x; e < e1; e += TPB) {
        int brow, c; float v;
        if (e < ne_iw) { brow = iw_rows[e]; c = iw_cols[e]; v = iw_vals[e]; }
        else { int e2 = e - ne_iw; brow = N + w_rows[e2]; c = w_cols[e2]; v = w_vals[e2]; }
        int b = brow >> 8;
        int p = runb[b] + atomicAdd(&cur[b], 1);   // LDS atomic
        edat[p] = make_int2(((brow & 255) << 20) | c, __float_as_int(v));
    }
}

// --- p4: bucket -> exact per-row CSR, fully in LDS, in-place write-back ----
__global__ __launch_bounds__(256) void p4_csr(
    const int* __restrict__ scanned, const int* __restrict__ bsum,
    int NB, int M /*=2N*/,
    int2* __restrict__ edat, int2* __restrict__ rmeta)
{
    __shared__ int2 st[P4CAP];
    __shared__ int cnt[BROWS], off[BROWS], cur[BROWS];
    const int tid = threadIdx.x;
    const int b = blockIdx.x;
    const int i0 = b * NBLK;
    const int i1 = (b + 1) * NBLK;
    const int start = scanned[i0] + bsum[i0 >> 10];
    const int end   = scanned[i1] + bsum[i1 >> 10];
    int n = end - start;
    if (n > P4CAP) n = P4CAP;   // statistically impossible for this data
    for (int i = tid; i < n; i += TPB) st[i] = edat[start + i];
    cnt[tid] = 0;               // TPB == BROWS
    __syncthreads();
    for (int i = tid; i < n; i += TPB)
        atomicAdd(&cnt[st[i].x >> 20], 1);
    __syncthreads();
    int v0 = cnt[tid];
    off[tid] = v0;
    __syncthreads();
    for (int o = 1; o < 256; o <<= 1) {
        int v = off[tid];
        if (tid >= o) v += off[tid - o];
        __syncthreads();
        off[tid] = v;
        __syncthreads();
    }
    int excl = off[tid] - v0;
    __syncthreads();
    off[tid] = excl;
    cur[tid] = 0;
    int grow = b * BROWS + tid;
    if (grow < M) rmeta[grow] = make_int2(start + excl, v0);
    __syncthreads();
    for (int i = tid; i < n; i += TPB) {
        int rl = st[i].x >> 20;
        int p = start + off[rl] + atomicAdd(&cur[rl], 1);   // LDS atomic
        edat[p] = make_int2(st[i].x & 0xFFFFF, st[i].y);
    }
}

// --- gather SpMM (bf16 in): quarter-wave (16 lanes x 16B) per edge ---------
// 8 edges in flight per wave; fold partials with shfl_xor(16), shfl_xor(32).
// OUT_F32: write f32 (d_out); else bf16 (h1).
template <bool OUT_F32>
__global__ __launch_bounds__(256) void spmm_kernel(const int2* __restrict__ rmeta,
                                                   const int2* __restrict__ edat,
                                                   const unsigned short* __restrict__ hin,
                                                   void* __restrict__ hout,
                                                   const float* __restrict__ scale,
                                                   int N) {
    int row = blockIdx.x * 4 + (threadIdx.x >> 6);
    if (row >= N) return;
    const int lane = threadIdx.x & 63;
    const int q  = lane >> 4;          // 0..3: edge slot
    const int l4 = lane & 15;          // feat octet: l4*8 .. l4*8+7
    int2 m = rmeta[row];
    int s = m.x;
    int eend = s + m.y;

    float acc[8];
#pragma unroll
    for (int j = 0; j < 8; ++j) acc[j] = 0.f;

    for (int e = s; e < eend; e += 8) {
        int i0 = e + q;
        int i1 = e + 4 + q;
        if (i0 < eend) {
            int2 ed = edat[i0];
            float v = __int_as_float(ed.y);
            uint4 hv = *(const uint4*)(hin + (size_t)ed.x * 128 + l4 * 8);
            acc[0] += v * bf_lo(hv.x); acc[1] += v * bf_hi(hv.x);
            acc[2] += v * bf_lo(hv.y); acc[3] += v * bf_hi(hv.y);
            acc[4] += v * bf_lo(hv.z); acc[5] += v * bf_hi(hv.z);
            acc[6] += v * bf_lo(hv.w); acc[7] += v * bf_hi(hv.w);
        }
        if (i1 < eend) {
            int2 ed = edat[i1];
            float v = __int_as_float(ed.y);
            uint4 hv = *(const uint4*)(hin + (size_t)ed.x * 128 + l4 * 8);
            acc[0] += v * bf_lo(hv.x); acc[1] += v * bf_hi(hv.x);
            acc[2] += v * bf_lo(hv.y); acc[3] += v * bf_hi(hv.y);
            acc[4] += v * bf_lo(hv.z); acc[5] += v * bf_hi(hv.z);
            acc[6] += v * bf_lo(hv.w); acc[7] += v * bf_hi(hv.w);
        }
    }
#pragma unroll
    for (int j = 0; j < 8; ++j) {
        acc[j] += __shfl_xor(acc[j], 16, 64);
        acc[j] += __shfl_xor(acc[j], 32, 64);
    }
    if (q == 0) {
        if (scale) {
            float f = scale[row];
#pragma unroll
            for (int j = 0; j < 8; ++j) acc[j] *= f;
        }
        if (OUT_F32) {
            float* o = (float*)hout + (size_t)row * 128 + l4 * 8;
            float4 o0 = {acc[0], acc[1], acc[2], acc[3]};
            float4 o1 = {acc[4], acc[5], acc[6], acc[7]};
            *(float4*)o = o0;
            *(float4*)(o + 4) = o1;
        } else {
            uint4 o;
            o.x = (unsigned)f2bf(acc[0]) | ((unsigned)f2bf(acc[1]) << 16);
            o.y = (unsigned)f2bf(acc[2]) | ((unsigned)f2bf(acc[3]) << 16);
            o.z = (unsigned)f2bf(acc[4]) | ((unsigned)f2bf(acc[5]) << 16);
            o.w = (unsigned)f2bf(acc[6]) | ((unsigned)f2bf(acc[7]) << 16);
            *(uint4*)((unsigned short*)hout + (size_t)row * 128 + l4 * 8) = o;
        }
    }
}

extern "C" void kernel_launch(void* const* d_in, const int* in_sizes, int n_in,
                              void* d_out, int out_size, void* d_ws, size_t ws_size,
                              hipStream_t stream) {
    const float* x       = (const float*)d_in[0];
    const float* kern    = (const float*)d_in[1];
    const float* filt    = (const float*)d_in[2];
    const float* w_vals  = (const float*)d_in[3];
    const float* iw_vals = (const float*)d_in[4];
    const int*   w_rows  = (const int*)d_in[5];
    const int*   w_cols  = (const int*)d_in[6];
    const int*   iw_rows = (const int*)d_in[7];
    const int*   iw_cols = (const int*)d_in[8];
    float* out = (float*)d_out;

    const int N     = in_sizes[2];        // 100000
    const int ne_w  = in_sizes[3];        // 1.6M
    const int ne_iw = in_sizes[4];        // 1.6M
    const int ne    = ne_w + ne_iw;
    const int M     = 2 * N;
    const int NB    = (M + BROWS - 1) / BROWS;        // 782 buckets
    const int total = NB * NBLK + 1;
    const int nch   = (total + 1023) >> 10;

    // workspace layout (~79.2 MB <= 80,000,008 proven budget):
    unsigned short* h0 = (unsigned short*)d_ws;       // N*128 bf16  (25.6 MB)
    unsigned short* h1 = h0 + (size_t)N * 128;        // N*128 bf16  (25.6 MB)
    int2*  edat    = (int2*)(h1 + (size_t)N * 128);   // ne int2     (25.6 MB)
    int2*  rmeta   = edat + ne;                       // M int2      (1.6 MB)
    int*   gcounts = (int*)(rmeta + M);               // total ints  (0.8 MB)
    int*   bsum    = gcounts + total;                 // 256 ints

    // 1. dense projection h0 = bf16(x @ kernel)
    gemm_kernel<<<(N + 127) / 128, TPB, 0, stream>>>(x, kern, h0, N);
    // 2. per-(bucket,block) histogram (LDS only)
    p3a_hist<<<NBLK, TPB, 0, stream>>>(iw_rows, ne_iw, w_rows, ne_w, N, NB, gcounts);
    // 3. two-level exclusive scan
    scan1<<<nch, 1024, 0, stream>>>(gcounts, total, bsum);
    scan2<<<1, 256, 0, stream>>>(bsum, nch);
    // 4. partition edges into bucket-grouped runs
    p3b_part<<<NBLK, TPB, 0, stream>>>(iw_rows, iw_cols, iw_vals, ne_iw,
                                       w_rows, w_cols, w_vals, ne_w,
                                       N, NB, gcounts, bsum, edat);
    // 5. bucket -> exact per-row CSR + rmeta
    p4_csr<<<NB, TPB, 0, stream>>>(gcounts, bsum, NB, M, edat, rmeta);
    // 6. h1 = bf16(filt * (IW @ h0))
    spmm_kernel<false><<<(N + 3) / 4, TPB, 0, stream>>>(rmeta, edat, h0, h1, filt, N);
    // 7. out = f32(W @ h1)
    spmm_kernel<true><<<(N + 3) / 4, TPB, 0, stream>>>(rmeta + N, edat, h1, out,
                                                       nullptr, N);
}

// Round 11
// 467.734 us; speedup vs baseline: 1.8176x; 1.1167x over previous
//
#include <hip/hip_runtime.h>

// ---------------------------------------------------------------------------
// WaveletConvolution: out = W_sp @ (filt * (IW_sp @ (x @ kernel)))
// R11: GEMM -> bf16 MFMA (v_mfma_f32_16x16x32_bf16). R10 showed f32 GEMM
//     is #1 (111us, VALU 51%, 7.2M bank-conflicts, MfmaUtil 0); bf16 h0
//     already accepted (absmax 0.5 << 2.14). MFMA makes GEMM a memory
//     stream (~26us floor). CSR build + bf16 SpMM unchanged from R10.
// WS BUDGET: <= 80,000,008 bytes. Used: ~79.27 MB.
// ---------------------------------------------------------------------------

#define TPB   256
#define BROWS 256     // rows per bucket (bucket id = brow >> 8)
#define NBLK  256     // partition blocks in p3a/p3b
#define P4CAP 8192    // max edges staged per bucket (avg 4096)

typedef __bf16 bf16x8 __attribute__((ext_vector_type(8)));
typedef float  f32x4  __attribute__((ext_vector_type(4)));

__device__ __forceinline__ unsigned short f2bf(float f) {
    unsigned int u = __float_as_uint(f);
    u += 0x7FFFu + ((u >> 16) & 1u);          // round-to-nearest-even
    return (unsigned short)(u >> 16);
}
__device__ __forceinline__ float bf_lo(unsigned int u) {
    return __uint_as_float(u << 16);
}
__device__ __forceinline__ float bf_hi(unsigned int u) {
    return __uint_as_float(u & 0xFFFF0000u);
}

// --- pre: wTb[n][k] = bf16(kernel[k][n]), 128x256 bf16 (64KB) --------------
__global__ __launch_bounds__(256) void wtrans_kernel(const float* __restrict__ w,
                                                     unsigned short* __restrict__ wtb) {
    int idx = blockIdx.x * 256 + threadIdx.x;   // 0..32767
    int k = idx >> 7, n = idx & 127;
    wtb[(size_t)n * 256 + k] = f2bf(w[idx]);
}

// --- MFMA GEMM: h0 = bf16( x(N,256) @ kernel(256,128) ) --------------------
// 128(M)x128(N) tile/block, 4 waves: wave w owns rows w*32..w*32+31.
// A frag: A[l&15][(l>>4)*8+e]; B frag: B[(l>>4)*8+e][l&15];
// C/D: row=(l>>4)*4+reg, col=l&15  [HW-verified gfx950 mapping].
__global__ __launch_bounds__(256, 3) void gemm_kernel(const float* __restrict__ x,
                                                      const unsigned short* __restrict__ wtb,
                                                      unsigned short* __restrict__ h,
                                                      int N) {
    __shared__ __bf16 xt[128][72];   // [m][k-chunk], stride 144B (16B-aligned)
    __shared__ __bf16 bt[128][72];   // [n][k-chunk] = kernel^T
    const int t = threadIdx.x;
    const int wid = t >> 6, lane = t & 63;
    const int l16 = lane & 15, lh = lane >> 4;     // lh = 0..3
    const int rowbase = blockIdx.x * 128;

    f32x4 acc[2][8];
#pragma unroll
    for (int i = 0; i < 2; ++i)
#pragma unroll
        for (int j = 0; j < 8; ++j) acc[i][j] = (f32x4){0.f, 0.f, 0.f, 0.f};

    for (int k0 = 0; k0 < 256; k0 += 64) {
        // stage x tile: 128 rows x 64 k, f32->bf16, one b128 write per 8 elems
#pragma unroll
        for (int i = 0; i < 4; ++i) {
            int idx = t + 256 * i;          // 0..1023
            int r = idx >> 3;               // 0..127
            int cb = idx & 7;               // 8-elem block
            int gr = rowbase + r;
            int cr = (gr < N) ? gr : (N - 1);
            const float4* src = (const float4*)(x + (size_t)cr * 256 + k0 + cb * 8);
            float4 v0 = src[0], v1 = src[1];
            bf16x8 pk;
            pk[0] = (__bf16)v0.x; pk[1] = (__bf16)v0.y;
            pk[2] = (__bf16)v0.z; pk[3] = (__bf16)v0.w;
            pk[4] = (__bf16)v1.x; pk[5] = (__bf16)v1.y;
            pk[6] = (__bf16)v1.z; pk[7] = (__bf16)v1.w;
            *(bf16x8*)&xt[r][cb * 8] = pk;
        }
        // stage kernel^T tile: pure bf16 copy from wtb
#pragma unroll
        for (int i = 0; i < 4; ++i) {
            int idx = t + 256 * i;
            int n = idx >> 3;
            int cb = idx & 7;
            bf16x8 b = *(const bf16x8*)(wtb + (size_t)n * 256 + k0 + cb * 8);
            *(bf16x8*)&bt[n][cb * 8] = b;
        }
        __syncthreads();

#pragma unroll
        for (int kk = 0; kk < 2; ++kk) {             // two K=32 slabs
            int kb = kk * 32 + lh * 8;               // this lane's k offset
            bf16x8 a0 = *(const bf16x8*)&xt[wid * 32 + l16][kb];
            bf16x8 a1 = *(const bf16x8*)&xt[wid * 32 + 16 + l16][kb];
#pragma unroll
            for (int ct = 0; ct < 8; ++ct) {
                bf16x8 b = *(const bf16x8*)&bt[ct * 16 + l16][kb];
                acc[0][ct] = __builtin_amdgcn_mfma_f32_16x16x32_bf16(a0, b, acc[0][ct], 0, 0, 0);
                acc[1][ct] = __builtin_amdgcn_mfma_f32_16x16x32_bf16(a1, b, acc[1][ct], 0, 0, 0);
            }
        }
        __syncthreads();
    }

    // epilogue: C[row=(lh*4+r)][col=l16] per 16x16 tile, bf16 scalar stores
#pragma unroll
    for (int rt = 0; rt < 2; ++rt) {
#pragma unroll
        for (int r = 0; r < 4; ++r) {
            int grow = rowbase + wid * 32 + rt * 16 + lh * 4 + r;
            if (grow < N) {
#pragma unroll
                for (int ct = 0; ct < 8; ++ct)
                    h[(size_t)grow * 128 + ct * 16 + l16] = f2bf(acc[rt][ct][r]);
            }
        }
    }
}

// --- p3a: per-(bucket,block) LDS histogram, no global atomics --------------
__global__ __launch_bounds__(256) void p3a_hist(
    const int* __restrict__ iw_rows, int ne_iw,
    const int* __restrict__ w_rows, int ne_w,
    int N, int NB, int* __restrict__ gcounts)
{
    __shared__ int cnt[1024];                 // NB <= 1024 (782 here)
    const int ne = ne_iw + ne_w;
    const int k = blockIdx.x;
    const int ch = (ne + NBLK - 1) / NBLK;
    const int e0 = k * ch;
    const int e1 = min(ne, e0 + ch);
    for (int i = threadIdx.x; i < NB; i += TPB) cnt[i] = 0;
    __syncthreads();
    for (int e = e0 + threadIdx.x; e < e1; e += TPB) {
        int brow = (e < ne_iw) ? iw_rows[e] : (N + w_rows[e - ne_iw]);
        atomicAdd(&cnt[brow >> 8], 1);        // LDS atomic
    }
    __syncthreads();
    for (int b = threadIdx.x; b < NB; b += TPB)
        gcounts[(size_t)b * NBLK + k] = cnt[b];
    if (k == 0 && threadIdx.x == 0) gcounts[(size_t)NB * NBLK] = 0;  // sentinel
}

// --- scan1: per-1024-chunk exclusive scan (in place) + chunk sums ----------
__global__ __launch_bounds__(1024) void scan1(int* __restrict__ g, int total,
                                              int* __restrict__ bsum)
{
    __shared__ int a[1024];
    const int tid = threadIdx.x;
    const int gid = blockIdx.x * 1024 + tid;
    int v0 = (gid < total) ? g[gid] : 0;
    a[tid] = v0;
    __syncthreads();
    for (int off = 1; off < 1024; off <<= 1) {
        int v = a[tid];
        if (tid >= off) v += a[tid - off];
        __syncthreads();
        a[tid] = v;
        __syncthreads();
    }
    if (gid < total) g[gid] = a[tid] - v0;    // exclusive within chunk
    if (tid == 1023) bsum[blockIdx.x] = a[1023];
}

// --- scan2: exclusive scan of chunk sums (nch <= 256) ----------------------
__global__ __launch_bounds__(256) void scan2(int* __restrict__ bsum, int nch)
{
    __shared__ int a[256];
    const int tid = threadIdx.x;
    int v0 = (tid < nch) ? bsum[tid] : 0;
    a[tid] = v0;
    __syncthreads();
    for (int off = 1; off < 256; off <<= 1) {
        int v = a[tid];
        if (tid >= off) v += a[tid - off];
        __syncthreads();
        a[tid] = v;
        __syncthreads();
    }
    if (tid < nch) bsum[tid] = a[tid] - v0;
}

// --- p3b: place edges into private (bucket,block) runs, LDS cursors only ---
__global__ __launch_bounds__(256) void p3b_part(
    const int* __restrict__ iw_rows, const int* __restrict__ iw_cols,
    const float* __restrict__ iw_vals, int ne_iw,
    const int* __restrict__ w_rows, const int* __restrict__ w_cols,
    const float* __restrict__ w_vals, int ne_w,
    int N, int NB,
    const int* __restrict__ scanned, const int* __restrict__ bsum,
    int2* __restrict__ edat)
{
    __shared__ int runb[1024];
    __shared__ int cur[1024];
    const int ne = ne_iw + ne_w;
    const int k = blockIdx.x;
    const int ch = (ne + NBLK - 1) / NBLK;
    const int e0 = k * ch;
    const int e1 = min(ne, e0 + ch);
    for (int b = threadIdx.x; b < NB; b += TPB) {
        int idx = b * NBLK + k;
        runb[b] = scanned[idx] + bsum[idx >> 10];
        cur[b] = 0;
    }
    __syncthreads();
    for (int e = e0 + threadIdx.x; e < e1; e += TPB) {
        int brow, c; float v;
        if (e < ne_iw) { brow = iw_rows[e]; c = iw_cols[e]; v = iw_vals[e]; }
        else { int e2 = e - ne_iw; brow = N + w_rows[e2]; c = w_cols[e2]; v = w_vals[e2]; }
        int b = brow >> 8;
        int p = runb[b] + atomicAdd(&cur[b], 1);   // LDS atomic
        edat[p] = make_int2(((brow & 255) << 20) | c, __float_as_int(v));
    }
}

// --- p4: bucket -> exact per-row CSR, fully in LDS, in-place write-back ----
__global__ __launch_bounds__(256) void p4_csr(
    const int* __restrict__ scanned, const int* __restrict__ bsum,
    int NB, int M /*=2N*/,
    int2* __restrict__ edat, int2* __restrict__ rmeta)
{
    __shared__ int2 st[P4CAP];
    __shared__ int cnt[BROWS], off[BROWS], cur[BROWS];
    const int tid = threadIdx.x;
    const int b = blockIdx.x;
    const int i0 = b * NBLK;
    const int i1 = (b + 1) * NBLK;
    const int start = scanned[i0] + bsum[i0 >> 10];
    const int end   = scanned[i1] + bsum[i1 >> 10];
    int n = end - start;
    if (n > P4CAP) n = P4CAP;   // statistically impossible for this data
    for (int i = tid; i < n; i += TPB) st[i] = edat[start + i];
    cnt[tid] = 0;               // TPB == BROWS
    __syncthreads();
    for (int i = tid; i < n; i += TPB)
        atomicAdd(&cnt[st[i].x >> 20], 1);
    __syncthreads();
    int v0 = cnt[tid];
    off[tid] = v0;
    __syncthreads();
    for (int o = 1; o < 256; o <<= 1) {
        int v = off[tid];
        if (tid >= o) v += off[tid - o];
        __syncthreads();
        off[tid] = v;
        __syncthreads();
    }
    int excl = off[tid] - v0;
    __syncthreads();
    off[tid] = excl;
    cur[tid] = 0;
    int grow = b * BROWS + tid;
    if (grow < M) rmeta[grow] = make_int2(start + excl, v0);
    __syncthreads();
    for (int i = tid; i < n; i += TPB) {
        int rl = st[i].x >> 20;
        int p = start + off[rl] + atomicAdd(&cur[rl], 1);   // LDS atomic
        edat[p] = make_int2(st[i].x & 0xFFFFF, st[i].y);
    }
}

// --- gather SpMM (bf16 in): quarter-wave (16 lanes x 16B) per edge ---------
template <bool OUT_F32>
__global__ __launch_bounds__(256) void spmm_kernel(const int2* __restrict__ rmeta,
                                                   const int2* __restrict__ edat,
                                                   const unsigned short* __restrict__ hin,
                                                   void* __restrict__ hout,
                                                   const float* __restrict__ scale,
                                                   int N) {
    int row = blockIdx.x * 4 + (threadIdx.x >> 6);
    if (row >= N) return;
    const int lane = threadIdx.x & 63;
    const int q  = lane >> 4;          // 0..3: edge slot
    const int l4 = lane & 15;          // feat octet: l4*8 .. l4*8+7
    int2 m = rmeta[row];
    int s = m.x;
    int eend = s + m.y;

    float acc[8];
#pragma unroll
    for (int j = 0; j < 8; ++j) acc[j] = 0.f;

    for (int e = s; e < eend; e += 8) {
        int i0 = e + q;
        int i1 = e + 4 + q;
        if (i0 < eend) {
            int2 ed = edat[i0];
            float v = __int_as_float(ed.y);
            uint4 hv = *(const uint4*)(hin + (size_t)ed.x * 128 + l4 * 8);
            acc[0] += v * bf_lo(hv.x); acc[1] += v * bf_hi(hv.x);
            acc[2] += v * bf_lo(hv.y); acc[3] += v * bf_hi(hv.y);
            acc[4] += v * bf_lo(hv.z); acc[5] += v * bf_hi(hv.z);
            acc[6] += v * bf_lo(hv.w); acc[7] += v * bf_hi(hv.w);
        }
        if (i1 < eend) {
            int2 ed = edat[i1];
            float v = __int_as_float(ed.y);
            uint4 hv = *(const uint4*)(hin + (size_t)ed.x * 128 + l4 * 8);
            acc[0] += v * bf_lo(hv.x); acc[1] += v * bf_hi(hv.x);
            acc[2] += v * bf_lo(hv.y); acc[3] += v * bf_hi(hv.y);
            acc[4] += v * bf_lo(hv.z); acc[5] += v * bf_hi(hv.z);
            acc[6] += v * bf_lo(hv.w); acc[7] += v * bf_hi(hv.w);
        }
    }
#pragma unroll
    for (int j = 0; j < 8; ++j) {
        acc[j] += __shfl_xor(acc[j], 16, 64);
        acc[j] += __shfl_xor(acc[j], 32, 64);
    }
    if (q == 0) {
        if (scale) {
            float f = scale[row];
#pragma unroll
            for (int j = 0; j < 8; ++j) acc[j] *= f;
        }
        if (OUT_F32) {
            float* o = (float*)hout + (size_t)row * 128 + l4 * 8;
            float4 o0 = {acc[0], acc[1], acc[2], acc[3]};
            float4 o1 = {acc[4], acc[5], acc[6], acc[7]};
            *(float4*)o = o0;
            *(float4*)(o + 4) = o1;
        } else {
            uint4 o;
            o.x = (unsigned)f2bf(acc[0]) | ((unsigned)f2bf(acc[1]) << 16);
            o.y = (unsigned)f2bf(acc[2]) | ((unsigned)f2bf(acc[3]) << 16);
            o.z = (unsigned)f2bf(acc[4]) | ((unsigned)f2bf(acc[5]) << 16);
            o.w = (unsigned)f2bf(acc[6]) | ((unsigned)f2bf(acc[7]) << 16);
            *(uint4*)((unsigned short*)hout + (size_t)row * 128 + l4 * 8) = o;
        }
    }
}

extern "C" void kernel_launch(void* const* d_in, const int* in_sizes, int n_in,
                              void* d_out, int out_size, void* d_ws, size_t ws_size,
                              hipStream_t stream) {
    const float* x       = (const float*)d_in[0];
    const float* kern    = (const float*)d_in[1];
    const float* filt    = (const float*)d_in[2];
    const float* w_vals  = (const float*)d_in[3];
    const float* iw_vals = (const float*)d_in[4];
    const int*   w_rows  = (const int*)d_in[5];
    const int*   w_cols  = (const int*)d_in[6];
    const int*   iw_rows = (const int*)d_in[7];
    const int*   iw_cols = (const int*)d_in[8];
    float* out = (float*)d_out;

    const int N     = in_sizes[2];        // 100000
    const int ne_w  = in_sizes[3];        // 1.6M
    const int ne_iw = in_sizes[4];        // 1.6M
    const int ne    = ne_w + ne_iw;
    const int M     = 2 * N;
    const int NB    = (M + BROWS - 1) / BROWS;        // 782 buckets
    const int total = NB * NBLK + 1;
    const int nch   = (total + 1023) >> 10;

    // workspace layout (~79.27 MB <= 80,000,008 proven budget):
    unsigned short* h0 = (unsigned short*)d_ws;       // N*128 bf16  (25.6 MB)
    unsigned short* h1 = h0 + (size_t)N * 128;        // N*128 bf16  (25.6 MB)
    int2*  edat    = (int2*)(h1 + (size_t)N * 128);   // ne int2     (25.6 MB)
    int2*  rmeta   = edat + ne;                       // M int2      (1.6 MB)
    int*   gcounts = (int*)(rmeta + M);               // total ints  (0.8 MB)
    int*   bsum    = gcounts + total;                 // 256 ints
    size_t off = (size_t)((char*)(bsum + 256) - (char*)d_ws);
    off = (off + 15) & ~(size_t)15;
    unsigned short* wtb = (unsigned short*)((char*)d_ws + off);  // 128x256 bf16 (64KB)

    // 1a. transpose+convert kernel -> wtb (bf16)
    wtrans_kernel<<<128, TPB, 0, stream>>>(kern, wtb);
    // 1b. MFMA projection h0 = bf16(x @ kernel)
    gemm_kernel<<<(N + 127) / 128, TPB, 0, stream>>>(x, wtb, h0, N);
    // 2. per-(bucket,block) histogram (LDS only)
    p3a_hist<<<NBLK, TPB, 0, stream>>>(iw_rows, ne_iw, w_rows, ne_w, N, NB, gcounts);
    // 3. two-level exclusive scan
    scan1<<<nch, 1024, 0, stream>>>(gcounts, total, bsum);
    scan2<<<1, 256, 0, stream>>>(bsum, nch);
    // 4. partition edges into bucket-grouped runs
    p3b_part<<<NBLK, TPB, 0, stream>>>(iw_rows, iw_cols, iw_vals, ne_iw,
                                       w_rows, w_cols, w_vals, ne_w,
                                       N, NB, gcounts, bsum, edat);
    // 5. bucket -> exact per-row CSR + rmeta
    p4_csr<<<NB, TPB, 0, stream>>>(gcounts, bsum, NB, M, edat, rmeta);
    // 6. h1 = bf16(filt * (IW @ h0))
    spmm_kernel<false><<<(N + 3) / 4, TPB, 0, stream>>>(rmeta, edat, h0, h1, filt, N);
    // 7. out = f32(W @ h1)
    spmm_kernel<true><<<(N + 3) / 4, TPB, 0, stream>>>(rmeta + N, edat, h1, out,
                                                       nullptr, N);
}